// Round 7
// baseline (495.645 us; speedup 1.0000x reference)
//
#include <hip/hip_runtime.h>
#include <stdint.h>

#define M_CH       384
#define TR         15
#define MARGIN     20
#define CHUNK_ROWS 16
#define BM_WORDS   192        // words per chunk = 16*384/32
#define WPR        12         // words per row = 384/32
#define WIN_ROWS   46         // CHUNK_ROWS + 2*TR
#define F4_PER_ROW 96         // 384 floats / 4

typedef float vfloat4 __attribute__((ext_vector_type(4)));  // native clang vec

// spread 8 bits of x to positions 0,4,8,...,28
__device__ __forceinline__ uint32_t spread4(uint32_t x) {
    x = (x | (x << 12)) & 0x000F000Fu;
    x = (x | (x << 6))  & 0x03030303u;
    x = (x | (x << 3))  & 0x11111111u;
    return x;
}

// ---------------- K0: neighbor masks + output pre-fill ----------------
// Block 0: per-channel neighbor word-masks. Blocks >=1: pre-fill output
// with -1 (emit overwrites [0,total)).
__global__ __launch_bounds__(256)
void init_kernel(const float* __restrict__ locs,
                 uint32_t* __restrict__ nEntries,
                 uint8_t* __restrict__ entryWord,
                 uint32_t* __restrict__ entryMask,
                 int maxdet, int* __restrict__ times, int* __restrict__ chans) {
    if ((int)blockIdx.x >= 1) {
        int i = ((int)blockIdx.x - 1) * 256 + threadIdx.x;
        if (i < maxdet) { times[i] = -1; chans[i] = -1; }
        return;
    }
    __shared__ float lx[M_CH], ly[M_CH];
    const int t = threadIdx.x;
    for (int c = t; c < M_CH; c += 256) {
        lx[c] = locs[2 * c];
        ly[c] = locs[2 * c + 1];
    }
    __syncthreads();
    for (int c0 = t; c0 < M_CH; c0 += 256) {
        float x = lx[c0], y = ly[c0];
        int ne = 0;
        for (int k = 0; k < WPR; ++k) {
            uint32_t mk = 0;
            #pragma unroll
            for (int b = 0; b < 32; ++b) {
                int c = k * 32 + b;
                float dx = x - lx[c], dy = y - ly[c];
                if (sqrtf(dx * dx + dy * dy) <= 100.0f) mk |= 1u << b;
            }
            if (mk) {
                entryWord[c0 * WPR + ne] = (uint8_t)k;
                entryMask[c0 * WPR + ne] = mk;
                ne++;
            }
        }
        nEntries[c0] = (uint32_t)ne;
    }
}

// ---------------- K1: FUSED threshold + validate + count ----------------
// Block = 192 threads = one 16-row chunk. The block's entire input is the
// CONTIGUOUS 46-row x 384-ch slab of traces (70.7 KB): load it with
// coalesced float4 reads, ballot-pack threshold bits directly into the LDS
// window (identical spread4 interleave -> identical word layout as the old
// cand pass), then validate from LDS exactly as before. No candWords
// buffer, no separate streaming kernel. Adjacent blocks overlap 30/46 rows
// -> slab re-reads are L2/L3 hits; unique HBM traffic stays ~230 MB.
__global__ __launch_bounds__(192)
void fused_validate_kernel(const float* __restrict__ traces, int N,
                           long n4, long nwords,
                           const uint32_t* __restrict__ nEntries,
                           const uint8_t* __restrict__ entryWord,
                           const uint32_t* __restrict__ entryMask,
                           uint32_t* __restrict__ validOut,
                           uint32_t* __restrict__ chunkCounts) {
    __shared__ uint32_t win[WIN_ROWS * WPR];   // 552 words = 2.2 KB
    __shared__ uint32_t red[3];
    const int t = threadIdx.x;
    const int lane = t & 63;
    const int wv   = t >> 6;                   // wave 0..2
    const int bid  = (int)blockIdx.x;
    const int r0   = bid * CHUNK_ROWS;

    // ---- stage: threshold-compare the slab, pack bits into win[] ----
    // Window = 552 words = 69 groups of 8 words; each group = 256 floats
    // = 64 float4 = one wave-iteration. Wave wv owns groups [wv*23, +23).
    {
        const long base4 = ((long)r0 - TR) * F4_PER_ROW;  // float4 idx of window start
        const bool full = (r0 - TR >= 0) && (r0 + CHUNK_ROWS + TR <= N);
        const int g  = lane >> 3;              // word 0..7 within group
        const int sh = 8 * g;                  // ballot byte for this word
        if (full) {
            #pragma unroll 4
            for (int it = 0; it < 23; ++it) {
                const int j = wv * 23 + it;
                vfloat4 v = ((const vfloat4*)traces)[base4 + (long)j * 64 + lane];
                uint64_t B0 = __ballot(v[0] <= -3.0f);
                uint64_t B1 = __ballot(v[1] <= -3.0f);
                uint64_t B2 = __ballot(v[2] <= -3.0f);
                uint64_t B3 = __ballot(v[3] <= -3.0f);
                uint32_t w = spread4((uint32_t)(B0 >> sh) & 0xFFu)
                           | (spread4((uint32_t)(B1 >> sh) & 0xFFu) << 1)
                           | (spread4((uint32_t)(B2 >> sh) & 0xFFu) << 2)
                           | (spread4((uint32_t)(B3 >> sh) & 0xFFu) << 3);
                if ((lane & 7) == 0) win[j * 8 + g] = w;
            }
        } else {
            for (int it = 0; it < 23; ++it) {
                const int j = wv * 23 + it;
                const long gi = base4 + (long)j * 64 + lane;
                vfloat4 v = (vfloat4)0.0f;     // rows outside [0,N) -> bit 0
                if (gi >= 0 && gi < n4) v = ((const vfloat4*)traces)[gi];
                uint64_t B0 = __ballot(v[0] <= -3.0f);
                uint64_t B1 = __ballot(v[1] <= -3.0f);
                uint64_t B2 = __ballot(v[2] <= -3.0f);
                uint64_t B3 = __ballot(v[3] <= -3.0f);
                uint32_t w = spread4((uint32_t)(B0 >> sh) & 0xFFu)
                           | (spread4((uint32_t)(B1 >> sh) & 0xFFu) << 1)
                           | (spread4((uint32_t)(B2 >> sh) & 0xFFu) << 2)
                           | (spread4((uint32_t)(B3 >> sh) & 0xFFu) << 3);
                if ((lane & 7) == 0) win[j * 8 + g] = w;
            }
        }
    }
    __syncthreads();

    const int lr = t / WPR;        // local row 0..15
    const int wi = t - lr * WPR;   // word-in-row 0..11
    const int r  = r0 + lr;
    const long w = (long)bid * BM_WORDS + t;

    uint32_t out = 0;
    if (w < nwords) {
        uint32_t word = win[(lr + TR) * WPR + wi];
        if (word && r >= MARGIN && r < N - MARGIN) {
            out = word;
            uint32_t tmp = word;
            while (tmp) {
                int bit = __ffs(tmp) - 1;
                tmp &= tmp - 1;
                const int c = wi * 32 + bit;
                const uint32_t selfbit = 1u << bit;
                const int ne = (int)nEntries[c];

                // ---- fast pass: any competitor bit anywhere in window? ----
                uint32_t anyComp = 0;
                for (int k = 0; k < ne; ++k) {
                    int wiE = (int)entryWord[c * WPR + k];
                    uint32_t em = entryMask[c * WPR + k];
                    const uint32_t* colp = &win[lr * WPR + wiE];
                    uint32_t orw = 0;
                    #pragma unroll
                    for (int dt = 0; dt < 31; ++dt) {
                        uint32_t h = colp[dt * WPR];
                        if (dt == TR) h &= (wiE == wi) ? ~selfbit : 0xFFFFFFFFu;
                        orw |= h & em;
                    }
                    anyComp |= orw;
                }

                if (anyComp) {
                    // ---- slow path: value comparison on actual hits ----
                    // (slab rows were just read -> L1/L2-hot)
                    float raw = traces[(long)r * M_CH + c];
                    bool bad = false;
                    for (int k = 0; k < ne && !bad; ++k) {
                        int wiE = (int)entryWord[c * WPR + k];
                        uint32_t em = entryMask[c * WPR + k];
                        const uint32_t* colp = &win[lr * WPR + wiE];
                        #pragma unroll
                        for (int dt = 0; dt < 31; ++dt) {
                            uint32_t h = colp[dt * WPR] & em;
                            if (dt == TR && wiE == wi) h &= ~selfbit;
                            while (h) {
                                int b2 = __ffs(h) - 1;
                                h &= h - 1;
                                float v = traces[(long)(r - TR + dt) * M_CH + wiE * 32 + b2];
                                if (v < raw) bad = true;
                            }
                        }
                    }
                    if (bad) out &= ~selfbit;
                }
            }
        }
        validOut[w] = out;
    }
    int pc = __popc(out);
    #pragma unroll
    for (int off = 32; off; off >>= 1) pc += __shfl_xor(pc, off, 64);
    if ((t & 63) == 0) red[t >> 6] = (uint32_t)pc;
    __syncthreads();
    if (t == 0) chunkCounts[blockIdx.x] = red[0] + red[1] + red[2];
}

// ---------------- K2: emit with REDUNDANT prefix (no scan kernel) --------
// Block handles 4 consecutive chunks (one per wave). Its base prefix is
// computed locally: 256 threads cooperatively sum counts[0..c0) — 37.5 KB
// of L1/L2-resident data, zero atomics, zero inter-block dependencies.
__global__ __launch_bounds__(256)
void emit_kernel(const uint32_t* __restrict__ validOut,
                 const uint32_t* __restrict__ chunkCounts,
                 int nchunk, int maxdet,
                 int* __restrict__ times, int* __restrict__ chans) {
    __shared__ uint32_t sred[4];
    __shared__ uint32_t cnts4[4];
    const int t = threadIdx.x;
    const int lane = t & 63;
    const int wv   = t >> 6;
    const int c0 = (int)blockIdx.x * 4;

    if (t < 4) cnts4[t] = (c0 + t < nchunk) ? chunkCounts[c0 + t] : 0u;

    // cooperative exclusive prefix: sum counts[0..c0)
    uint32_t part = 0;
    for (int i = t; i < c0; i += 256) part += chunkCounts[i];
    #pragma unroll
    for (int off = 32; off; off >>= 1) part += __shfl_xor(part, off, 64);
    if (lane == 0) sred[wv] = part;
    __syncthreads();
    uint32_t base0 = sred[0] + sred[1] + sred[2] + sred[3];

    const int chunkId = c0 + wv;
    if (chunkId >= nchunk) return;
    uint32_t basePref = base0;
    #pragma unroll
    for (int k = 0; k < 3; ++k) if (k < wv) basePref += cnts4[k];

    const uint32_t* wp = validOut + (long)chunkId * BM_WORDS + lane * 3;
    uint32_t b0 = wp[0], b1 = wp[1], b2 = wp[2];
    int local = __popc(b0) + __popc(b1) + __popc(b2);

    int s = local;
    #pragma unroll
    for (int off = 1; off < 64; off <<= 1) {
        int v = __shfl_up(s, off, 64);
        if (lane >= off) s += v;
    }
    int base = (int)basePref + (s - local);
    int r0 = chunkId * CHUNK_ROWS;

    uint32_t words[3] = { b0, b1, b2 };
    #pragma unroll
    for (int q = 0; q < 3; ++q) {
        uint32_t x = words[q];
        int fbase = (lane * 3 + q) * 32;
        while (x) {
            int b = __ffs(x) - 1;
            x &= x - 1;
            int f = fbase + b;
            int n = f / M_CH;
            int ch = f - n * M_CH;
            if (base < maxdet) {
                times[base] = r0 + n;
                chans[base] = ch;
            }
            base++;
        }
    }
}

extern "C" void kernel_launch(void* const* d_in, const int* in_sizes, int n_in,
                              void* d_out, int out_size, void* d_ws, size_t ws_size,
                              hipStream_t stream) {
    const float* traces = (const float*)d_in[0];
    const float* locs   = (const float*)d_in[1];
    const int M = M_CH;
    const int N = in_sizes[0] / M;            // 150000
    const long nsamp = (long)N * M;           // 57,600,000
    const int maxdet = out_size / 2;          // 100000
    int* times = (int*)d_out;
    int* chans = times + maxdet;

    const long n4     = nsamp / 4;                          // 14,400,000
    const long nwords = nsamp / 32;                         // 1,800,000
    const int  nchunk = (N + CHUNK_ROWS - 1) / CHUNK_ROWS;  // 9375

    char* ws = (char*)d_ws;
    uint32_t* nEntries    = (uint32_t*)(ws + 0);            // 1536
    uint8_t*  entryWord   = (uint8_t*)(ws + 1536);          // 4608   -> 6144
    uint32_t* entryMask   = (uint32_t*)(ws + 6144);         // 18432  -> 24576
    uint32_t* chunkCounts = (uint32_t*)(ws + 24576);        // 37500  -> 65536 (pad)
    uint32_t* validOut    = (uint32_t*)(ws + 65536);        // 7.2 MB

    // K0: nbr masks (block 0) + output pre-fill (rest)
    const int fillBlocks = (maxdet + 255) / 256;            // 391
    init_kernel<<<1 + fillBlocks, 256, 0, stream>>>(
        locs, nEntries, entryWord, entryMask, maxdet, times, chans);

    // K1: fused threshold+validate+count (one block per 16-row chunk)
    fused_validate_kernel<<<nchunk, BM_WORDS, 0, stream>>>(
        traces, N, n4, nwords, nEntries, entryWord, entryMask,
        validOut, chunkCounts);

    // K2: ordered emit with redundant prefix
    const int emitBlocks = (nchunk + 3) / 4;                // 2344
    emit_kernel<<<emitBlocks, 256, 0, stream>>>(
        validOut, chunkCounts, nchunk, maxdet, times, chans);
}